// Round 3
// baseline (18152.342 us; speedup 1.0000x reference)
//
#include <hip/hip_runtime.h>
#include <cmath>

typedef _Float16 half8  __attribute__((ext_vector_type(8)));
typedef _Float16 half4v __attribute__((ext_vector_type(4)));
typedef float    float4v __attribute__((ext_vector_type(4)));

// ---------------------------------------------------------------------------
// MFMA conv3x3 (SAME), fp16 in / fp32 acc / fp16 out (relu).
// Pre-padded NHWC fp16 input; guard ring holds zeros (or real halo).
// WG = 256 thr = 4 waves; wave tile = (MT*16) co x 144 px (9 n-tiles).
// A (weights) from LDS, stored in read-order [tap][mt][lane] -> conflict-free
// ds_read_b128. B (pixels) direct from global (L1/L2-served, tap re-reads).
// IMG mode folds batch into blockIdx.x (64 tiles per image).
// ---------------------------------------------------------------------------
template<int MT>
__global__ __launch_bounds__(256, 4)
void mfma_conv(const _Float16* __restrict__ in, const _Float16* __restrict__ Wg,
               const float* __restrict__ bias, _Float16* __restrict__ out,
               int CI, int CO, int RSin, int RSout, int IMG)
{
    __shared__ __align__(16) _Float16 sW[9 * MT * 64 * 8];

    const int tid  = threadIdx.x;
    const int wave = tid >> 6;
    const int lane = tid & 63;
    const int ll   = lane & 15;          // px index within n-tile
    const int quad = lane >> 4;          // k-group
    const int co0  = blockIdx.y * (MT * 16);
    const int bx   = blockIdx.x;

    size_t in_base, out_base;
    if (IMG) {
        int tile = bx & 63, b = bx >> 6;
        int ty = tile >> 3, tx = tile & 7;
        in_base  = (size_t)b * RSin * RSin * CI  + (size_t)(ty * 24 * RSin  + tx * 24) * CI;
        out_base = (size_t)b * RSout * RSout * CO + (size_t)(ty * 24 * RSout + tx * 24) * CO;
    } else {
        in_base  = (size_t)bx * 676 * CI;
        out_base = (size_t)bx * 676 * CO;
    }

    int b_off[9];
    #pragma unroll
    for (int nt = 0; nt < 9; ++nt) {
        int p = wave * 144 + nt * 16 + ll;
        b_off[nt] = (p / 24) * RSin * CI + (p % 24) * CI;
    }
    int tapoff[9];
    #pragma unroll
    for (int dy = 0; dy < 3; ++dy)
        #pragma unroll
        for (int dx = 0; dx < 3; ++dx)
            tapoff[dy * 3 + dx] = (dy * RSin + dx) * CI;

    float4v acc[MT][9];
    #pragma unroll
    for (int mt = 0; mt < MT; ++mt)
        #pragma unroll
        for (int nt = 0; nt < 9; ++nt)
            acc[mt][nt] = (float4v){0.f, 0.f, 0.f, 0.f};

    for (int ci0 = 0; ci0 < CI; ci0 += 32) {
        __syncthreads();
        // stage weights in read-order: slot s = (t*MT+mt)*64 + lane
        for (int c = tid; c < 9 * MT * 64; c += 256) {
            int lane_s = c & 63;
            int mtt = c >> 6;            // t*MT + mt
            int mt = mtt % MT, t = mtt / MT;
            *(uint4*)&sW[(size_t)c * 8] =
                *(const uint4*)&Wg[((size_t)(co0 + mt * 16 + (lane_s & 15)) * 9 + t) * CI
                                   + ci0 + (lane_s >> 4) * 8];
        }
        __syncthreads();

        const _Float16* inp = in + in_base + ci0 + quad * 8;
        #pragma unroll
        for (int t = 0; t < 9; ++t) {
            half8 a[MT];
            #pragma unroll
            for (int mt = 0; mt < MT; ++mt)
                a[mt] = *(const half8*)&sW[((t * MT + mt) * 64 + lane) * 8];
            const int toff = tapoff[t];
            #pragma unroll
            for (int nt = 0; nt < 9; ++nt) {
                half8 b = *(const half8*)(inp + b_off[nt] + toff);
                #pragma unroll
                for (int mt = 0; mt < MT; ++mt)
                    acc[mt][nt] = __builtin_amdgcn_mfma_f32_16x16x32_f16(
                        a[mt], b, acc[mt][nt], 0, 0, 0);
            }
        }
    }

    // epilogue: bias + relu -> fp16, D layout col=lane&15 (px), row=quad*4+reg (co)
    #pragma unroll
    for (int mt = 0; mt < MT; ++mt) {
        float4v bs = *(const float4v*)&bias[co0 + mt * 16 + quad * 4];
        #pragma unroll
        for (int nt = 0; nt < 9; ++nt) {
            int p = wave * 144 + nt * 16 + ll;
            size_t ooff = out_base
                + (size_t)((p / 24 + 1) * RSout + (p % 24) + 1) * CO
                + co0 + mt * 16 + quad * 4;
            float4v v = acc[mt][nt];
            half4v h;
            h.x = (_Float16)fmaxf(v.x + bs.x, 0.f);
            h.y = (_Float16)fmaxf(v.y + bs.y, 0.f);
            h.z = (_Float16)fmaxf(v.z + bs.z, 0.f);
            h.w = (_Float16)fmaxf(v.w + bs.w, 0.f);
            *(half4v*)(out + ooff) = h;
        }
    }
}

// ---------------------------------------------------------------------------
// helpers
// ---------------------------------------------------------------------------
// fp32 NCHW src/tgt -> padded NHWC fp16 image interior [2][194][194][128]
__global__ __launch_bounds__(256)
void build_x16i(const float* __restrict__ src, const float* __restrict__ tgt,
                _Float16* __restrict__ X)
{
    int idx = blockIdx.x * 256 + threadIdx.x;
    int q = idx & 15, pid = idx >> 4;
    if (pid >= 2 * 36864) return;
    int b = pid / 36864, r = pid % 36864;
    int y = r / 192, x = r % 192;
    half8 h;
    #pragma unroll
    for (int j = 0; j < 8; ++j) {
        int ch = q * 8 + j;
        const float* im = (ch < 64) ? src : tgt;
        h[j] = (_Float16)im[(size_t)(b * 64 + (ch & 63)) * 36864 + r];
    }
    *(half8*)&X[(((size_t)b * 194 + y + 1) * 194 + (x + 1)) * 128 + q * 8] = h;
}

// fp32 OIHW -> fp16 [co][tap][ci]
__global__ __launch_bounds__(256)
void cvt_w(const float* __restrict__ src, _Float16* __restrict__ dst, int CO, int CI)
{
    int idx = blockIdx.x * 256 + threadIdx.x;
    if (idx >= CO * 9 * CI) return;
    int ci = idx % CI, t = (idx / CI) % 9, co = idx / (9 * CI);
    dst[idx] = (_Float16)src[((size_t)co * CI + ci) * 9 + t];
}

// gather nP patches from padded image into padded per-patch buffer (zero ring)
__global__ __launch_bounds__(256)
void g_patch(const _Float16* __restrict__ X, _Float16* __restrict__ P1, int p0, int nP)
{
    int idx = blockIdx.x * 256 + threadIdx.x;
    if (idx >= nP * 676 * 16) return;
    int q = idx & 15, t2 = idx >> 4;
    int r676 = t2 % 676, pl = t2 / 676;
    int pr = r676 / 26, pc = r676 % 26;
    int P = p0 + pl;
    int b = P / 225, rem = P % 225, pi = rem / 15, pj = rem % 15;
    uint4 v = {0u, 0u, 0u, 0u};
    if (pr >= 1 && pr <= 24 && pc >= 1 && pc <= 24)
        v = *(const uint4*)&X[(((size_t)b * 194 + pi * 12 + pr) * 194 + (pj * 12 + pc)) * 128 + q * 8];
    *(uint4*)&P1[((size_t)pl * 676 + r676) * 128 + q * 8] = v;
}

// zero the guard ring of a padded NHWC buffer [npatch][RS][RS][CI]
__global__ __launch_bounds__(256)
void ring_zero(_Float16* __restrict__ buf, int npatch, int RS, int CI)
{
    int c8 = CI >> 3;
    int RC = 2 * RS + 2 * (RS - 2);
    int idx = blockIdx.x * 256 + threadIdx.x;
    if (idx >= npatch * RC * c8) return;
    int q = idx % c8, rp = (idx / c8) % RC, pl = idx / (c8 * RC);
    int r, c;
    if (rp < RS)            { r = 0;      c = rp; }
    else if (rp < 2 * RS)   { r = RS - 1; c = rp - RS; }
    else {
        int s = rp - 2 * RS, half = RS - 2;
        if (s < half) { r = s + 1;        c = 0; }
        else          { r = s - half + 1; c = RS - 1; }
    }
    uint4 z = {0u, 0u, 0u, 0u};
    *(uint4*)&buf[((size_t)pl * RS * RS + r * RS + c) * CI + q * 8] = z;
}

// conv3 (M=1) sigmoid over padded D2 [nP][26][26][256] -> score fp32
__global__ __launch_bounds__(256)
void conv3_sig(const _Float16* __restrict__ D2, const _Float16* __restrict__ W3h,
               const float* __restrict__ b3, float* __restrict__ score, int p0, int nP)
{
    int idx = blockIdx.x * 256 + threadIdx.x;
    if (idx >= nP * 576) return;
    int pl = idx / 576, p = idx % 576, py = p / 24, px = p % 24;
    float acc = b3[0];
    for (int dy = 0; dy < 3; ++dy)
        for (int dx = 0; dx < 3; ++dx) {
            const _Float16* base = D2 + ((size_t)pl * 676 + (py + dy) * 26 + (px + dx)) * 256;
            const _Float16* wb = W3h + (dy * 3 + dx) * 256;
            for (int c = 0; c < 256; c += 8) {
                half8 v = *(const half8*)(base + c);
                half8 w = *(const half8*)(wb + c);
                #pragma unroll
                for (int j = 0; j < 8; ++j) acc += (float)v[j] * (float)w[j];
            }
        }
    score[(size_t)(p0 + pl) * 576 + p] = 1.f / (1.f + expf(-acc));
}

// conv3 (M=1) tanh over padded A2 [194][194][64] -> out fp32 (one batch)
__global__ __launch_bounds__(256)
void conv3_tanh(const _Float16* __restrict__ A2, const _Float16* __restrict__ Wh,
                const float* __restrict__ br3, float* __restrict__ out)
{
    int idx = blockIdx.x * 256 + threadIdx.x;
    if (idx >= 36864) return;
    int y = idx / 192, x = idx % 192;
    float acc = br3[0];
    for (int dy = 0; dy < 3; ++dy)
        for (int dx = 0; dx < 3; ++dx) {
            const _Float16* base = A2 + ((size_t)(y + dy) * 194 + (x + dx)) * 64;
            const _Float16* wb = Wh + (dy * 3 + dx) * 64;
            for (int c = 0; c < 64; c += 8) {
                half8 v = *(const half8*)(base + c);
                half8 w = *(const half8*)(wb + c);
                #pragma unroll
                for (int j = 0; j < 8; ++j) acc += (float)v[j] * (float)w[j];
            }
        }
    out[idx] = tanhf(acc);
}

// overlap-add normalize (coverage closed-form)
__global__ __launch_bounds__(256)
void att_finalize(const float* __restrict__ score, float* __restrict__ out)
{
    int idx = blockIdx.x * 256 + threadIdx.x;
    if (idx >= 2 * 36864) return;
    int b = idx / 36864, r = idx % 36864;
    int y = r / 192, x = r % 192;
    int i_lo = (y >= 24) ? (y - 12) / 12 : 0;
    int i_hi = min(14, y / 12);
    int j_lo = (x >= 24) ? (x - 12) / 12 : 0;
    int j_hi = min(14, x / 12);
    float s = 0.f; int cnt = 0;
    for (int i = i_lo; i <= i_hi; ++i)
        for (int j = j_lo; j <= j_hi; ++j) {
            s += score[(((size_t)b * 15 + i) * 15 + j) * 576 + (y - 12 * i) * 24 + (x - 12 * j)];
            ++cnt;
        }
    out[idx] = s / (float)cnt;
}

// ---------------------------------------------------------------------------
extern "C" void kernel_launch(void* const* d_in, const int* in_sizes, int n_in,
                              void* d_out, int out_size, void* d_ws, size_t ws_size,
                              hipStream_t stream)
{
    const float* src = (const float*)d_in[0];
    const float* tgt = (const float*)d_in[1];
    const float* W1  = (const float*)d_in[2];  const float* b1  = (const float*)d_in[3];
    const float* W2  = (const float*)d_in[4];  const float* b2  = (const float*)d_in[5];
    const float* W3  = (const float*)d_in[6];  const float* b3  = (const float*)d_in[7];
    const float* Wr1 = (const float*)d_in[8];  const float* br1 = (const float*)d_in[9];
    const float* Wr2 = (const float*)d_in[10]; const float* br2 = (const float*)d_in[11];
    const float* Wr3 = (const float*)d_in[12]; const float* br3 = (const float*)d_in[13];
    float* out = (float*)d_out;

    // ---- fixed workspace (halves) ----
    _Float16* ws = (_Float16*)d_ws;
    size_t o = 0;
    _Float16* X16i = ws + o; o += (size_t)2 * 194 * 194 * 128;   // 9,634,816
    _Float16* W1h  = ws + o; o += (size_t)512 * 9 * 128;
    _Float16* W2h  = ws + o; o += (size_t)256 * 9 * 512;
    _Float16* Wr1h = ws + o; o += (size_t)512 * 9 * 128;
    _Float16* Wr2h = ws + o; o += (size_t)64 * 9 * 512;
    _Float16* W3h  = ws + o; o += 9 * 256;
    _Float16* Wr3h = ws + o; o += 9 * 64;
    float*    score = (float*)(ws + o); o += 2 * 259200;
    const size_t fixed_h = o;

    // ---- adaptive patch chunking by ws_size ----
    const size_t per_patch_h = (size_t)676 * (128 + 512 + 256);  // 605,696
    const size_t reg_h = (size_t)194 * 194 * (512 + 64);         // 21,676,416
    int P = 50;
    {
        size_t h_avail = ws_size / 2;
        size_t need450 = fixed_h + ((450 * per_patch_h > reg_h) ? 450 * per_patch_h : reg_h);
        size_t need150 = fixed_h + ((150 * per_patch_h > reg_h) ? 150 * per_patch_h : reg_h);
        if (h_avail >= need450)      P = 450;
        else if (h_avail >= need150) P = 150;
    }
    const int nchunks = 450 / P;

    _Float16* P1 = ws + fixed_h;
    _Float16* D1 = P1 + (size_t)P * 676 * 128;
    _Float16* D2 = D1 + (size_t)P * 676 * 512;
    _Float16* A1 = P1;                                           // reg region reuse
    _Float16* A2 = A1 + (size_t)194 * 194 * 512;

    // ---- precompute fp16 operands ----
    ring_zero<<<(2 * (2 * 194 + 2 * 192) * 16 + 255) / 256, 256, 0, stream>>>(X16i, 2, 194, 128);
    build_x16i<<<4608, 256, 0, stream>>>(src, tgt, X16i);
    cvt_w<<<2304, 256, 0, stream>>>(W1,  W1h,  512, 128);
    cvt_w<<<4608, 256, 0, stream>>>(W2,  W2h,  256, 512);
    cvt_w<<<2304, 256, 0, stream>>>(Wr1, Wr1h, 512, 128);
    cvt_w<<<1152, 256, 0, stream>>>(Wr2, Wr2h, 64,  512);
    cvt_w<<<9,    256, 0, stream>>>(W3,  W3h,  1,   256);
    cvt_w<<<3,    256, 0, stream>>>(Wr3, Wr3h, 1,   64);

    // ---- attention path ----
    ring_zero<<<(P * 100 * 64 + 255) / 256, 256, 0, stream>>>(D1, P, 26, 512);
    ring_zero<<<(P * 100 * 32 + 255) / 256, 256, 0, stream>>>(D2, P, 26, 256);
    for (int c = 0; c < nchunks; ++c) {
        int p0 = c * P;
        g_patch<<<(P * 676 * 16 + 255) / 256, 256, 0, stream>>>(X16i, P1, p0, P);
        mfma_conv<4><<<dim3(P, 8), 256, 0, stream>>>(P1, W1h, b1, D1, 128, 512, 26, 26, 0);
        mfma_conv<4><<<dim3(P, 4), 256, 0, stream>>>(D1, W2h, b2, D2, 512, 256, 26, 26, 0);
        conv3_sig<<<(P * 576 + 255) / 256, 256, 0, stream>>>(D2, W3h, b3, score, p0, P);
    }
    att_finalize<<<288, 256, 0, stream>>>(score, out + 73728);

    // ---- registration path (batch folded into grid.x) ----
    ring_zero<<<(2 * (2 * 194 + 2 * 192) * 64 + 255) / 256, 256, 0, stream>>>(A1, 1, 194, 512);
    ring_zero<<<(2 * (2 * 194 + 2 * 192) * 8  + 255) / 256, 256, 0, stream>>>(A2, 1, 194, 64);
    // NOTE: A1/A2 hold ONE batch at a time is no longer true — we fold batch, so
    // allocate per-batch regions inside A1/A2 strides (IMG mode uses b*RS*RS*CI).
    // A1 region must hold 2 batches: 2*194*194*512 exceeds P=50 region? ->
    // run per-batch sequentially when P==50 to stay within workspace.
    if (P >= 150) {
        // two-batch A1/A2 fit in the chunk region when P>=150
        _Float16* A2b = A1 + (size_t)2 * 194 * 194 * 512;
        ring_zero<<<(2 * (2 * 194 + 2 * 192) * 64 + 255) / 256, 256, 0, stream>>>(A1, 2, 194, 512);
        ring_zero<<<(2 * (2 * 194 + 2 * 192) * 8  + 255) / 256, 256, 0, stream>>>(A2b, 2, 194, 64);
        mfma_conv<4><<<dim3(128, 8), 256, 0, stream>>>(X16i, Wr1h, br1, A1, 128, 512, 194, 194, 1);
        mfma_conv<2><<<dim3(128, 2), 256, 0, stream>>>(A1, Wr2h, br2, A2b, 512, 64, 194, 194, 1);
        for (int b = 0; b < 2; ++b)
            conv3_tanh<<<144, 256, 0, stream>>>(A2b + (size_t)b * 194 * 194 * 64, Wr3h, br3,
                                                out + b * 36864);
    } else {
        for (int b = 0; b < 2; ++b) {
            ring_zero<<<(1 * (2 * 194 + 2 * 192) * 64 + 255) / 256, 256, 0, stream>>>(A1, 1, 194, 512);
            ring_zero<<<(1 * (2 * 194 + 2 * 192) * 8  + 255) / 256, 256, 0, stream>>>(A2, 1, 194, 64);
            mfma_conv<4><<<dim3(64, 8), 256, 0, stream>>>(X16i + (size_t)b * 194 * 194 * 128,
                                                          Wr1h, br1, A1, 128, 512, 194, 194, 1);
            mfma_conv<2><<<dim3(64, 2), 256, 0, stream>>>(A1, Wr2h, br2, A2, 512, 64, 194, 194, 1);
            conv3_tanh<<<144, 256, 0, stream>>>(A2, Wr3h, br3, out + b * 36864);
        }
    }
}

// Round 4
// 4118.503 us; speedup vs baseline: 4.4075x; 4.4075x over previous
//
#include <hip/hip_runtime.h>
#include <cmath>

typedef _Float16 half8  __attribute__((ext_vector_type(8)));
typedef _Float16 half4v __attribute__((ext_vector_type(4)));
typedef float    float4v __attribute__((ext_vector_type(4)));

// ---------------------------------------------------------------------------
// MFMA conv3x3 (SAME), fp16 in / fp32 acc / fp16 out (relu).
// Pre-padded NHWC fp16 input; guard ring holds zeros (or real halo).
// WG = 256 thr = 4 waves; wave tile = (MT*16) co x 144 px (9 n-tiles).
// A (weights) from LDS, stored in read-order [tap][mt][lane] -> conflict-free
// ds_read_b128 (SQ_LDS_BANK_CONFLICT==0 measured R3). B (pixels) direct from
// global (L1/L2-served tap re-reads). IMG mode folds batch into blockIdx.x.
// launch_bounds: (256,2) — 256-VGPR budget. (256,4) spilled the 144 acc VGPRs
// to scratch (R3: 7.5 GB HBM writes, 14x regression). Do not raise.
// ---------------------------------------------------------------------------
template<int MT>
__global__ __launch_bounds__(256, 2)
void mfma_conv(const _Float16* __restrict__ in, const _Float16* __restrict__ Wg,
               const float* __restrict__ bias, _Float16* __restrict__ out,
               int CI, int CO, int RSin, int RSout, int IMG)
{
    __shared__ __align__(16) _Float16 sW[9 * MT * 64 * 8];

    const int tid  = threadIdx.x;
    const int wave = tid >> 6;
    const int lane = tid & 63;
    const int ll   = lane & 15;          // px index within n-tile
    const int quad = lane >> 4;          // k-group
    const int co0  = blockIdx.y * (MT * 16);
    const int bx   = blockIdx.x;

    size_t in_base, out_base;
    if (IMG) {
        int tile = bx & 63, b = bx >> 6;
        int ty = tile >> 3, tx = tile & 7;
        in_base  = (size_t)b * RSin * RSin * CI  + (size_t)(ty * 24 * RSin  + tx * 24) * CI;
        out_base = (size_t)b * RSout * RSout * CO + (size_t)(ty * 24 * RSout + tx * 24) * CO;
    } else {
        in_base  = (size_t)bx * 676 * CI;
        out_base = (size_t)bx * 676 * CO;
    }

    int b_off[9];
    #pragma unroll
    for (int nt = 0; nt < 9; ++nt) {
        int p = wave * 144 + nt * 16 + ll;
        b_off[nt] = (p / 24) * RSin * CI + (p % 24) * CI;
    }
    int tapoff[9];
    #pragma unroll
    for (int dy = 0; dy < 3; ++dy)
        #pragma unroll
        for (int dx = 0; dx < 3; ++dx)
            tapoff[dy * 3 + dx] = (dy * RSin + dx) * CI;

    float4v acc[MT][9];
    #pragma unroll
    for (int mt = 0; mt < MT; ++mt)
        #pragma unroll
        for (int nt = 0; nt < 9; ++nt)
            acc[mt][nt] = (float4v){0.f, 0.f, 0.f, 0.f};

    for (int ci0 = 0; ci0 < CI; ci0 += 32) {
        __syncthreads();
        // stage weights in read-order: slot s = (t*MT+mt)*64 + lane
        for (int c = tid; c < 9 * MT * 64; c += 256) {
            int lane_s = c & 63;
            int mtt = c >> 6;            // t*MT + mt
            int mt = mtt % MT, t = mtt / MT;
            *(uint4*)&sW[(size_t)c * 8] =
                *(const uint4*)&Wg[((size_t)(co0 + mt * 16 + (lane_s & 15)) * 9 + t) * CI
                                   + ci0 + (lane_s >> 4) * 8];
        }
        __syncthreads();

        const _Float16* inp = in + in_base + ci0 + quad * 8;
        #pragma unroll
        for (int t = 0; t < 9; ++t) {
            half8 a[MT];
            #pragma unroll
            for (int mt = 0; mt < MT; ++mt)
                a[mt] = *(const half8*)&sW[((t * MT + mt) * 64 + lane) * 8];
            const int toff = tapoff[t];
            #pragma unroll
            for (int nt = 0; nt < 9; ++nt) {
                half8 b = *(const half8*)(inp + b_off[nt] + toff);
                #pragma unroll
                for (int mt = 0; mt < MT; ++mt)
                    acc[mt][nt] = __builtin_amdgcn_mfma_f32_16x16x32_f16(
                        a[mt], b, acc[mt][nt], 0, 0, 0);
            }
        }
    }

    // epilogue: bias + relu -> fp16, D layout col=lane&15 (px), row=quad*4+reg (co)
    #pragma unroll
    for (int mt = 0; mt < MT; ++mt) {
        float4v bs = *(const float4v*)&bias[co0 + mt * 16 + quad * 4];
        #pragma unroll
        for (int nt = 0; nt < 9; ++nt) {
            int p = wave * 144 + nt * 16 + ll;
            size_t ooff = out_base
                + (size_t)((p / 24 + 1) * RSout + (p % 24) + 1) * CO
                + co0 + mt * 16 + quad * 4;
            float4v v = acc[mt][nt];
            half4v h;
            h.x = (_Float16)fmaxf(v.x + bs.x, 0.f);
            h.y = (_Float16)fmaxf(v.y + bs.y, 0.f);
            h.z = (_Float16)fmaxf(v.z + bs.z, 0.f);
            h.w = (_Float16)fmaxf(v.w + bs.w, 0.f);
            *(half4v*)(out + ooff) = h;
        }
    }
}

// ---------------------------------------------------------------------------
// helpers
// ---------------------------------------------------------------------------
// fp32 NCHW src/tgt -> padded NHWC fp16 image interior [2][194][194][128]
__global__ __launch_bounds__(256)
void build_x16i(const float* __restrict__ src, const float* __restrict__ tgt,
                _Float16* __restrict__ X)
{
    int idx = blockIdx.x * 256 + threadIdx.x;
    int q = idx & 15, pid = idx >> 4;
    if (pid >= 2 * 36864) return;
    int b = pid / 36864, r = pid % 36864;
    int y = r / 192, x = r % 192;
    half8 h;
    #pragma unroll
    for (int j = 0; j < 8; ++j) {
        int ch = q * 8 + j;
        const float* im = (ch < 64) ? src : tgt;
        h[j] = (_Float16)im[(size_t)(b * 64 + (ch & 63)) * 36864 + r];
    }
    *(half8*)&X[(((size_t)b * 194 + y + 1) * 194 + (x + 1)) * 128 + q * 8] = h;
}

// fp32 OIHW -> fp16 [co][tap][ci]
__global__ __launch_bounds__(256)
void cvt_w(const float* __restrict__ src, _Float16* __restrict__ dst, int CO, int CI)
{
    int idx = blockIdx.x * 256 + threadIdx.x;
    if (idx >= CO * 9 * CI) return;
    int ci = idx % CI, t = (idx / CI) % 9, co = idx / (9 * CI);
    dst[idx] = (_Float16)src[((size_t)co * CI + ci) * 9 + t];
}

// gather nP patches from padded image into padded per-patch buffer
__global__ __launch_bounds__(256)
void g_patch(const _Float16* __restrict__ X, _Float16* __restrict__ P1, int p0, int nP)
{
    int idx = blockIdx.x * 256 + threadIdx.x;
    if (idx >= nP * 676 * 16) return;
    int q = idx & 15, t2 = idx >> 4;
    int r676 = t2 % 676, pl = t2 / 676;
    int pr = r676 / 26, pc = r676 % 26;
    int P = p0 + pl;
    int b = P / 225, rem = P % 225, pi = rem / 15, pj = rem % 15;
    uint4 v = {0u, 0u, 0u, 0u};
    if (pr >= 1 && pr <= 24 && pc >= 1 && pc <= 24)
        v = *(const uint4*)&X[(((size_t)b * 194 + pi * 12 + pr) * 194 + (pj * 12 + pc)) * 128 + q * 8];
    *(uint4*)&P1[((size_t)pl * 676 + r676) * 128 + q * 8] = v;
}

// zero the guard ring of a padded NHWC buffer [npatch][RS][RS][CI]
__global__ __launch_bounds__(256)
void ring_zero(_Float16* __restrict__ buf, int npatch, int RS, int CI)
{
    int c8 = CI >> 3;
    int RC = 2 * RS + 2 * (RS - 2);
    int idx = blockIdx.x * 256 + threadIdx.x;
    if (idx >= npatch * RC * c8) return;
    int q = idx % c8, rp = (idx / c8) % RC, pl = idx / (c8 * RC);
    int r, c;
    if (rp < RS)            { r = 0;      c = rp; }
    else if (rp < 2 * RS)   { r = RS - 1; c = rp - RS; }
    else {
        int s = rp - 2 * RS, half = RS - 2;
        if (s < half) { r = s + 1;        c = 0; }
        else          { r = s - half + 1; c = RS - 1; }
    }
    uint4 z = {0u, 0u, 0u, 0u};
    *(uint4*)&buf[((size_t)pl * RS * RS + r * RS + c) * CI + q * 8] = z;
}

// conv3 (M=1) sigmoid over padded D2 [nP][26][26][256] -> score fp32
__global__ __launch_bounds__(256)
void conv3_sig(const _Float16* __restrict__ D2, const _Float16* __restrict__ W3h,
               const float* __restrict__ b3, float* __restrict__ score, int p0, int nP)
{
    int idx = blockIdx.x * 256 + threadIdx.x;
    if (idx >= nP * 576) return;
    int pl = idx / 576, p = idx % 576, py = p / 24, px = p % 24;
    float acc = b3[0];
    for (int dy = 0; dy < 3; ++dy)
        for (int dx = 0; dx < 3; ++dx) {
            const _Float16* base = D2 + ((size_t)pl * 676 + (py + dy) * 26 + (px + dx)) * 256;
            const _Float16* wb = W3h + (dy * 3 + dx) * 256;
            for (int c = 0; c < 256; c += 8) {
                half8 v = *(const half8*)(base + c);
                half8 w = *(const half8*)(wb + c);
                #pragma unroll
                for (int j = 0; j < 8; ++j) acc += (float)v[j] * (float)w[j];
            }
        }
    score[(size_t)(p0 + pl) * 576 + p] = 1.f / (1.f + expf(-acc));
}

// conv3 (M=1) tanh over padded A2 [194][194][64] -> out fp32 (one batch)
__global__ __launch_bounds__(256)
void conv3_tanh(const _Float16* __restrict__ A2, const _Float16* __restrict__ Wh,
                const float* __restrict__ br3, float* __restrict__ out)
{
    int idx = blockIdx.x * 256 + threadIdx.x;
    if (idx >= 36864) return;
    int y = idx / 192, x = idx % 192;
    float acc = br3[0];
    for (int dy = 0; dy < 3; ++dy)
        for (int dx = 0; dx < 3; ++dx) {
            const _Float16* base = A2 + ((size_t)(y + dy) * 194 + (x + dx)) * 64;
            const _Float16* wb = Wh + (dy * 3 + dx) * 64;
            for (int c = 0; c < 64; c += 8) {
                half8 v = *(const half8*)(base + c);
                half8 w = *(const half8*)(wb + c);
                #pragma unroll
                for (int j = 0; j < 8; ++j) acc += (float)v[j] * (float)w[j];
            }
        }
    out[idx] = tanhf(acc);
}

// overlap-add normalize (coverage closed-form)
__global__ __launch_bounds__(256)
void att_finalize(const float* __restrict__ score, float* __restrict__ out)
{
    int idx = blockIdx.x * 256 + threadIdx.x;
    if (idx >= 2 * 36864) return;
    int b = idx / 36864, r = idx % 36864;
    int y = r / 192, x = r % 192;
    int i_lo = (y >= 24) ? (y - 12) / 12 : 0;
    int i_hi = min(14, y / 12);
    int j_lo = (x >= 24) ? (x - 12) / 12 : 0;
    int j_hi = min(14, x / 12);
    float s = 0.f; int cnt = 0;
    for (int i = i_lo; i <= i_hi; ++i)
        for (int j = j_lo; j <= j_hi; ++j) {
            s += score[(((size_t)b * 15 + i) * 15 + j) * 576 + (y - 12 * i) * 24 + (x - 12 * j)];
            ++cnt;
        }
    out[idx] = s / (float)cnt;
}

// ---------------------------------------------------------------------------
extern "C" void kernel_launch(void* const* d_in, const int* in_sizes, int n_in,
                              void* d_out, int out_size, void* d_ws, size_t ws_size,
                              hipStream_t stream)
{
    const float* src = (const float*)d_in[0];
    const float* tgt = (const float*)d_in[1];
    const float* W1  = (const float*)d_in[2];  const float* b1  = (const float*)d_in[3];
    const float* W2  = (const float*)d_in[4];  const float* b2  = (const float*)d_in[5];
    const float* W3  = (const float*)d_in[6];  const float* b3  = (const float*)d_in[7];
    const float* Wr1 = (const float*)d_in[8];  const float* br1 = (const float*)d_in[9];
    const float* Wr2 = (const float*)d_in[10]; const float* br2 = (const float*)d_in[11];
    const float* Wr3 = (const float*)d_in[12]; const float* br3 = (const float*)d_in[13];
    float* out = (float*)d_out;

    // ---- fixed workspace (halves) ----
    _Float16* ws = (_Float16*)d_ws;
    size_t o = 0;
    _Float16* X16i = ws + o; o += (size_t)2 * 194 * 194 * 128;
    _Float16* W1h  = ws + o; o += (size_t)512 * 9 * 128;
    _Float16* W2h  = ws + o; o += (size_t)256 * 9 * 512;
    _Float16* Wr1h = ws + o; o += (size_t)512 * 9 * 128;
    _Float16* Wr2h = ws + o; o += (size_t)64 * 9 * 512;
    _Float16* W3h  = ws + o; o += 9 * 256;
    _Float16* Wr3h = ws + o; o += 9 * 64;
    float*    score = (float*)(ws + o); o += 2 * 259200;
    const size_t fixed_h = o;

    // ---- adaptive patch chunking by ws_size ----
    const size_t per_patch_h = (size_t)676 * (128 + 512 + 256);  // 605,696
    const size_t reg_h = (size_t)194 * 194 * (512 + 64);         // 21,676,416
    int P = 50;
    {
        size_t h_avail = ws_size / 2;
        size_t need450 = fixed_h + ((450 * per_patch_h > 2 * reg_h) ? 450 * per_patch_h : 2 * reg_h);
        size_t need150 = fixed_h + ((150 * per_patch_h > 2 * reg_h) ? 150 * per_patch_h : 2 * reg_h);
        if (h_avail >= need450)      P = 450;
        else if (h_avail >= need150) P = 150;
    }
    const int nchunks = 450 / P;

    _Float16* P1 = ws + fixed_h;
    _Float16* D1 = P1 + (size_t)P * 676 * 128;
    _Float16* D2 = D1 + (size_t)P * 676 * 512;
    _Float16* A1 = P1;                                           // reg region reuse
    _Float16* A2 = A1 + (size_t)194 * 194 * 512;

    // ---- precompute fp16 operands ----
    ring_zero<<<(2 * (2 * 194 + 2 * 192) * 16 + 255) / 256, 256, 0, stream>>>(X16i, 2, 194, 128);
    build_x16i<<<4608, 256, 0, stream>>>(src, tgt, X16i);
    cvt_w<<<2304, 256, 0, stream>>>(W1,  W1h,  512, 128);
    cvt_w<<<4608, 256, 0, stream>>>(W2,  W2h,  256, 512);
    cvt_w<<<2304, 256, 0, stream>>>(Wr1, Wr1h, 512, 128);
    cvt_w<<<1152, 256, 0, stream>>>(Wr2, Wr2h, 64,  512);
    cvt_w<<<9,    256, 0, stream>>>(W3,  W3h,  1,   256);
    cvt_w<<<3,    256, 0, stream>>>(Wr3, Wr3h, 1,   64);

    // ---- attention path ----
    ring_zero<<<(P * 100 * 64 + 255) / 256, 256, 0, stream>>>(D1, P, 26, 512);
    ring_zero<<<(P * 100 * 32 + 255) / 256, 256, 0, stream>>>(D2, P, 26, 256);
    for (int c = 0; c < nchunks; ++c) {
        int p0 = c * P;
        g_patch<<<(P * 676 * 16 + 255) / 256, 256, 0, stream>>>(X16i, P1, p0, P);
        mfma_conv<4><<<dim3(P, 8), 256, 0, stream>>>(P1, W1h, b1, D1, 128, 512, 26, 26, 0);
        mfma_conv<4><<<dim3(P, 4), 256, 0, stream>>>(D1, W2h, b2, D2, 512, 256, 26, 26, 0);
        conv3_sig<<<(P * 576 + 255) / 256, 256, 0, stream>>>(D2, W3h, b3, score, p0, P);
    }
    att_finalize<<<288, 256, 0, stream>>>(score, out + 73728);

    // ---- registration path ----
    if (P >= 150) {
        // batch-folded: A1 holds 2 batches (chunk region is large enough)
        _Float16* A2b = A1 + (size_t)2 * 194 * 194 * 512;
        ring_zero<<<(2 * (2 * 194 + 2 * 192) * 64 + 255) / 256, 256, 0, stream>>>(A1, 2, 194, 512);
        ring_zero<<<(2 * (2 * 194 + 2 * 192) * 8  + 255) / 256, 256, 0, stream>>>(A2b, 2, 194, 64);
        mfma_conv<4><<<dim3(128, 8), 256, 0, stream>>>(X16i, Wr1h, br1, A1, 128, 512, 194, 194, 1);
        mfma_conv<2><<<dim3(128, 2), 256, 0, stream>>>(A1, Wr2h, br2, A2b, 512, 64, 194, 194, 1);
        for (int b = 0; b < 2; ++b)
            conv3_tanh<<<144, 256, 0, stream>>>(A2b + (size_t)b * 194 * 194 * 64, Wr3h, br3,
                                                out + b * 36864);
    } else {
        for (int b = 0; b < 2; ++b) {
            ring_zero<<<(1 * (2 * 194 + 2 * 192) * 64 + 255) / 256, 256, 0, stream>>>(A1, 1, 194, 512);
            ring_zero<<<(1 * (2 * 194 + 2 * 192) * 8  + 255) / 256, 256, 0, stream>>>(A2, 1, 194, 64);
            mfma_conv<4><<<dim3(64, 8), 256, 0, stream>>>(X16i + (size_t)b * 194 * 194 * 128,
                                                          Wr1h, br1, A1, 128, 512, 194, 194, 1);
            mfma_conv<2><<<dim3(64, 2), 256, 0, stream>>>(A1, Wr2h, br2, A2, 512, 64, 194, 194, 1);
            conv3_tanh<<<144, 256, 0, stream>>>(A2, Wr3h, br3, out + b * 36864);
        }
    }
}

// Round 5
// 3143.985 us; speedup vs baseline: 5.7737x; 1.3100x over previous
//
#include <hip/hip_runtime.h>
#include <cmath>

typedef _Float16 half8  __attribute__((ext_vector_type(8)));
typedef _Float16 half4v __attribute__((ext_vector_type(4)));
typedef float    float4v __attribute__((ext_vector_type(4)));

// ---------------------------------------------------------------------------
// MFMA conv3x3 (SAME), fp16 in / fp32 acc / fp16 out (relu).
// Pre-padded NHWC fp16 input; guard ring holds zeros (or real halo).
// WG = 256 thr = 4 waves; wave tile = (MT*16) co x 144 px (9 n-tiles).
// A (weights) from LDS in read-order [tap][mt][lane] (conflict-free, R3/R4:
// SQ_LDS_BANK_CONFLICT==0). B (pixels) direct from global.
// launch_bounds (256,2): 256-VGPR budget. (256,4) spilled accs (R3, 14x). Keep.
//
// R5: 1-D grid + XCD swizzle. HW maps block id -> XCD round-robin (id%8).
// id = xcd + 8*(group*NC + co_t); px_block = group*8 + xcd. All NC co-tiles
// of one px-block run adjacently ON THE SAME XCD -> its activation slab
// (<=692 KB) stays in that XCD's 4 MB L2 for all NC x 9-tap re-reads.
// R4 (co-variants 450 ids apart): conv2 FETCH=1.77GB (~5.7x unique).
// ---------------------------------------------------------------------------
template<int MT>
__global__ __launch_bounds__(256, 2)
void mfma_conv(const _Float16* __restrict__ in, const _Float16* __restrict__ Wg,
               const float* __restrict__ bias, _Float16* __restrict__ out,
               int CI, int CO, int RSin, int RSout, int IMG, int NB, int NC)
{
    __shared__ __align__(16) _Float16 sW[9 * MT * 64 * 8];

    const int tid  = threadIdx.x;
    const int wave = tid >> 6;
    const int lane = tid & 63;
    const int ll   = lane & 15;          // px index within n-tile
    const int quad = lane >> 4;          // k-group

    // XCD-locality decode (whole block uniform; early-exit is barrier-safe)
    const int id   = blockIdx.x;
    const int xcd  = id & 7;
    const int slot = id >> 3;
    const int px_b = (slot / NC) * 8 + xcd;
    const int co_t = slot % NC;
    if (px_b >= NB) return;
    const int co0 = co_t * (MT * 16);

    size_t in_base, out_base;
    if (IMG) {
        int tile = px_b & 63, b = px_b >> 6;
        int ty = tile >> 3, tx = tile & 7;
        in_base  = (size_t)b * RSin * RSin * CI   + (size_t)(ty * 24 * RSin  + tx * 24) * CI;
        out_base = (size_t)b * RSout * RSout * CO + (size_t)(ty * 24 * RSout + tx * 24) * CO;
    } else {
        in_base  = (size_t)px_b * 676 * CI;
        out_base = (size_t)px_b * 676 * CO;
    }

    int b_off[9];
    #pragma unroll
    for (int nt = 0; nt < 9; ++nt) {
        int p = wave * 144 + nt * 16 + ll;
        b_off[nt] = (p / 24) * RSin * CI + (p % 24) * CI;
    }
    int tapoff[9];
    #pragma unroll
    for (int dy = 0; dy < 3; ++dy)
        #pragma unroll
        for (int dx = 0; dx < 3; ++dx)
            tapoff[dy * 3 + dx] = (dy * RSin + dx) * CI;

    float4v acc[MT][9];
    #pragma unroll
    for (int mt = 0; mt < MT; ++mt)
        #pragma unroll
        for (int nt = 0; nt < 9; ++nt)
            acc[mt][nt] = (float4v){0.f, 0.f, 0.f, 0.f};

    for (int ci0 = 0; ci0 < CI; ci0 += 32) {
        __syncthreads();
        // stage weights in read-order: slot s = (t*MT+mt)*64 + lane
        for (int c = tid; c < 9 * MT * 64; c += 256) {
            int lane_s = c & 63;
            int mtt = c >> 6;            // t*MT + mt
            int mt = mtt % MT, t = mtt / MT;
            *(uint4*)&sW[(size_t)c * 8] =
                *(const uint4*)&Wg[((size_t)(co0 + mt * 16 + (lane_s & 15)) * 9 + t) * CI
                                   + ci0 + (lane_s >> 4) * 8];
        }
        __syncthreads();

        const _Float16* inp = in + in_base + ci0 + quad * 8;
        #pragma unroll
        for (int t = 0; t < 9; ++t) {
            half8 a[MT];
            #pragma unroll
            for (int mt = 0; mt < MT; ++mt)
                a[mt] = *(const half8*)&sW[((t * MT + mt) * 64 + lane) * 8];
            const int toff = tapoff[t];
            #pragma unroll
            for (int nt = 0; nt < 9; ++nt) {
                half8 b = *(const half8*)(inp + b_off[nt] + toff);
                #pragma unroll
                for (int mt = 0; mt < MT; ++mt)
                    acc[mt][nt] = __builtin_amdgcn_mfma_f32_16x16x32_f16(
                        a[mt], b, acc[mt][nt], 0, 0, 0);
            }
        }
    }

    // epilogue: bias + relu -> fp16, D layout col=lane&15 (px), row=quad*4+reg (co)
    #pragma unroll
    for (int mt = 0; mt < MT; ++mt) {
        float4v bs = *(const float4v*)&bias[co0 + mt * 16 + quad * 4];
        #pragma unroll
        for (int nt = 0; nt < 9; ++nt) {
            int p = wave * 144 + nt * 16 + ll;
            size_t ooff = out_base
                + (size_t)((p / 24 + 1) * RSout + (p % 24) + 1) * CO
                + co0 + mt * 16 + quad * 4;
            float4v v = acc[mt][nt];
            half4v h;
            h.x = (_Float16)fmaxf(v.x + bs.x, 0.f);
            h.y = (_Float16)fmaxf(v.y + bs.y, 0.f);
            h.z = (_Float16)fmaxf(v.z + bs.z, 0.f);
            h.w = (_Float16)fmaxf(v.w + bs.w, 0.f);
            *(half4v*)(out + ooff) = h;
        }
    }
}

static inline int swiz_grid(int NB, int NC) { return ((NB + 7) & ~7) * NC; }

// ---------------------------------------------------------------------------
// helpers
// ---------------------------------------------------------------------------
// fp32 NCHW src/tgt -> padded NHWC fp16 image interior [2][194][194][128]
__global__ __launch_bounds__(256)
void build_x16i(const float* __restrict__ src, const float* __restrict__ tgt,
                _Float16* __restrict__ X)
{
    int idx = blockIdx.x * 256 + threadIdx.x;
    int q = idx & 15, pid = idx >> 4;
    if (pid >= 2 * 36864) return;
    int b = pid / 36864, r = pid % 36864;
    int y = r / 192, x = r % 192;
    half8 h;
    #pragma unroll
    for (int j = 0; j < 8; ++j) {
        int ch = q * 8 + j;
        const float* im = (ch < 64) ? src : tgt;
        h[j] = (_Float16)im[(size_t)(b * 64 + (ch & 63)) * 36864 + r];
    }
    *(half8*)&X[(((size_t)b * 194 + y + 1) * 194 + (x + 1)) * 128 + q * 8] = h;
}

// fp32 OIHW -> fp16 [co][tap][ci]
__global__ __launch_bounds__(256)
void cvt_w(const float* __restrict__ src, _Float16* __restrict__ dst, int CO, int CI)
{
    int idx = blockIdx.x * 256 + threadIdx.x;
    if (idx >= CO * 9 * CI) return;
    int ci = idx % CI, t = (idx / CI) % 9, co = idx / (9 * CI);
    dst[idx] = (_Float16)src[((size_t)co * CI + ci) * 9 + t];
}

// gather nP patches from padded image into padded per-patch buffer
__global__ __launch_bounds__(256)
void g_patch(const _Float16* __restrict__ X, _Float16* __restrict__ P1, int p0, int nP)
{
    int idx = blockIdx.x * 256 + threadIdx.x;
    if (idx >= nP * 676 * 16) return;
    int q = idx & 15, t2 = idx >> 4;
    int r676 = t2 % 676, pl = t2 / 676;
    int pr = r676 / 26, pc = r676 % 26;
    int P = p0 + pl;
    int b = P / 225, rem = P % 225, pi = rem / 15, pj = rem % 15;
    uint4 v = {0u, 0u, 0u, 0u};
    if (pr >= 1 && pr <= 24 && pc >= 1 && pc <= 24)
        v = *(const uint4*)&X[(((size_t)b * 194 + pi * 12 + pr) * 194 + (pj * 12 + pc)) * 128 + q * 8];
    *(uint4*)&P1[((size_t)pl * 676 + r676) * 128 + q * 8] = v;
}

// zero the guard ring of a padded NHWC buffer [npatch][RS][RS][CI]
__global__ __launch_bounds__(256)
void ring_zero(_Float16* __restrict__ buf, int npatch, int RS, int CI)
{
    int c8 = CI >> 3;
    int RC = 2 * RS + 2 * (RS - 2);
    int idx = blockIdx.x * 256 + threadIdx.x;
    if (idx >= npatch * RC * c8) return;
    int q = idx % c8, rp = (idx / c8) % RC, pl = idx / (c8 * RC);
    int r, c;
    if (rp < RS)            { r = 0;      c = rp; }
    else if (rp < 2 * RS)   { r = RS - 1; c = rp - RS; }
    else {
        int s = rp - 2 * RS, half = RS - 2;
        if (s < half) { r = s + 1;        c = 0; }
        else          { r = s - half + 1; c = RS - 1; }
    }
    uint4 z = {0u, 0u, 0u, 0u};
    *(uint4*)&buf[((size_t)pl * RS * RS + r * RS + c) * CI + q * 8] = z;
}

// conv3 (M=1) sigmoid over padded D2 [nP][26][26][256] -> score fp32
__global__ __launch_bounds__(256)
void conv3_sig(const _Float16* __restrict__ D2, const _Float16* __restrict__ W3h,
               const float* __restrict__ b3, float* __restrict__ score, int p0, int nP)
{
    int idx = blockIdx.x * 256 + threadIdx.x;
    if (idx >= nP * 576) return;
    int pl = idx / 576, p = idx % 576, py = p / 24, px = p % 24;
    float acc = b3[0];
    for (int dy = 0; dy < 3; ++dy)
        for (int dx = 0; dx < 3; ++dx) {
            const _Float16* base = D2 + ((size_t)pl * 676 + (py + dy) * 26 + (px + dx)) * 256;
            const _Float16* wb = W3h + (dy * 3 + dx) * 256;
            for (int c = 0; c < 256; c += 8) {
                half8 v = *(const half8*)(base + c);
                half8 w = *(const half8*)(wb + c);
                #pragma unroll
                for (int j = 0; j < 8; ++j) acc += (float)v[j] * (float)w[j];
            }
        }
    score[(size_t)(p0 + pl) * 576 + p] = 1.f / (1.f + expf(-acc));
}

// conv3 (M=1) tanh over padded A2 [194][194][64] -> out fp32 (one batch)
__global__ __launch_bounds__(256)
void conv3_tanh(const _Float16* __restrict__ A2, const _Float16* __restrict__ Wh,
                const float* __restrict__ br3, float* __restrict__ out)
{
    int idx = blockIdx.x * 256 + threadIdx.x;
    if (idx >= 36864) return;
    int y = idx / 192, x = idx % 192;
    float acc = br3[0];
    for (int dy = 0; dy < 3; ++dy)
        for (int dx = 0; dx < 3; ++dx) {
            const _Float16* base = A2 + ((size_t)(y + dy) * 194 + (x + dx)) * 64;
            const _Float16* wb = Wh + (dy * 3 + dx) * 64;
            for (int c = 0; c < 64; c += 8) {
                half8 v = *(const half8*)(base + c);
                half8 w = *(const half8*)(wb + c);
                #pragma unroll
                for (int j = 0; j < 8; ++j) acc += (float)v[j] * (float)w[j];
            }
        }
    out[idx] = tanhf(acc);
}

// overlap-add normalize (coverage closed-form)
__global__ __launch_bounds__(256)
void att_finalize(const float* __restrict__ score, float* __restrict__ out)
{
    int idx = blockIdx.x * 256 + threadIdx.x;
    if (idx >= 2 * 36864) return;
    int b = idx / 36864, r = idx % 36864;
    int y = r / 192, x = r % 192;
    int i_lo = (y >= 24) ? (y - 12) / 12 : 0;
    int i_hi = min(14, y / 12);
    int j_lo = (x >= 24) ? (x - 12) / 12 : 0;
    int j_hi = min(14, x / 12);
    float s = 0.f; int cnt = 0;
    for (int i = i_lo; i <= i_hi; ++i)
        for (int j = j_lo; j <= j_hi; ++j) {
            s += score[(((size_t)b * 15 + i) * 15 + j) * 576 + (y - 12 * i) * 24 + (x - 12 * j)];
            ++cnt;
        }
    out[idx] = s / (float)cnt;
}

// ---------------------------------------------------------------------------
extern "C" void kernel_launch(void* const* d_in, const int* in_sizes, int n_in,
                              void* d_out, int out_size, void* d_ws, size_t ws_size,
                              hipStream_t stream)
{
    const float* src = (const float*)d_in[0];
    const float* tgt = (const float*)d_in[1];
    const float* W1  = (const float*)d_in[2];  const float* b1  = (const float*)d_in[3];
    const float* W2  = (const float*)d_in[4];  const float* b2  = (const float*)d_in[5];
    const float* W3  = (const float*)d_in[6];  const float* b3  = (const float*)d_in[7];
    const float* Wr1 = (const float*)d_in[8];  const float* br1 = (const float*)d_in[9];
    const float* Wr2 = (const float*)d_in[10]; const float* br2 = (const float*)d_in[11];
    const float* Wr3 = (const float*)d_in[12]; const float* br3 = (const float*)d_in[13];
    float* out = (float*)d_out;

    // ---- fixed workspace (halves) ----
    _Float16* ws = (_Float16*)d_ws;
    size_t o = 0;
    _Float16* X16i = ws + o; o += (size_t)2 * 194 * 194 * 128;
    _Float16* W1h  = ws + o; o += (size_t)512 * 9 * 128;
    _Float16* W2h  = ws + o; o += (size_t)256 * 9 * 512;
    _Float16* Wr1h = ws + o; o += (size_t)512 * 9 * 128;
    _Float16* Wr2h = ws + o; o += (size_t)64 * 9 * 512;
    _Float16* W3h  = ws + o; o += 9 * 256;
    _Float16* Wr3h = ws + o; o += 9 * 64;
    float*    score = (float*)(ws + o); o += 2 * 259200;
    const size_t fixed_h = o;

    // ---- adaptive patch chunking by ws_size ----
    const size_t per_patch_h = (size_t)676 * (128 + 512 + 256);  // 605,696
    const size_t reg_h = (size_t)194 * 194 * (512 + 64);         // 21,676,416
    int P = 50;
    {
        size_t h_avail = ws_size / 2;
        size_t need450 = fixed_h + ((450 * per_patch_h > 2 * reg_h) ? 450 * per_patch_h : 2 * reg_h);
        size_t need150 = fixed_h + ((150 * per_patch_h > 2 * reg_h) ? 150 * per_patch_h : 2 * reg_h);
        if (h_avail >= need450)      P = 450;
        else if (h_avail >= need150) P = 150;
    }
    const int nchunks = 450 / P;

    _Float16* P1 = ws + fixed_h;
    _Float16* D1 = P1 + (size_t)P * 676 * 128;
    _Float16* D2 = D1 + (size_t)P * 676 * 512;
    _Float16* A1 = P1;                                           // reg region reuse
    _Float16* A2 = A1 + (size_t)194 * 194 * 512;

    // ---- precompute fp16 operands ----
    ring_zero<<<(2 * (2 * 194 + 2 * 192) * 16 + 255) / 256, 256, 0, stream>>>(X16i, 2, 194, 128);
    build_x16i<<<4608, 256, 0, stream>>>(src, tgt, X16i);
    cvt_w<<<2304, 256, 0, stream>>>(W1,  W1h,  512, 128);
    cvt_w<<<4608, 256, 0, stream>>>(W2,  W2h,  256, 512);
    cvt_w<<<2304, 256, 0, stream>>>(Wr1, Wr1h, 512, 128);
    cvt_w<<<1152, 256, 0, stream>>>(Wr2, Wr2h, 64,  512);
    cvt_w<<<9,    256, 0, stream>>>(W3,  W3h,  1,   256);
    cvt_w<<<3,    256, 0, stream>>>(Wr3, Wr3h, 1,   64);

    // ---- attention path ----
    ring_zero<<<(P * 100 * 64 + 255) / 256, 256, 0, stream>>>(D1, P, 26, 512);
    ring_zero<<<(P * 100 * 32 + 255) / 256, 256, 0, stream>>>(D2, P, 26, 256);
    for (int c = 0; c < nchunks; ++c) {
        int p0 = c * P;
        g_patch<<<(P * 676 * 16 + 255) / 256, 256, 0, stream>>>(X16i, P1, p0, P);
        mfma_conv<4><<<swiz_grid(P, 8), 256, 0, stream>>>(P1, W1h, b1, D1, 128, 512, 26, 26, 0, P, 8);
        mfma_conv<4><<<swiz_grid(P, 4), 256, 0, stream>>>(D1, W2h, b2, D2, 512, 256, 26, 26, 0, P, 4);
        conv3_sig<<<(P * 576 + 255) / 256, 256, 0, stream>>>(D2, W3h, b3, score, p0, P);
    }
    att_finalize<<<288, 256, 0, stream>>>(score, out + 73728);

    // ---- registration path ----
    if (P >= 150) {
        // batch-folded: A1 holds 2 batches (chunk region is large enough)
        _Float16* A2b = A1 + (size_t)2 * 194 * 194 * 512;
        ring_zero<<<(2 * (2 * 194 + 2 * 192) * 64 + 255) / 256, 256, 0, stream>>>(A1, 2, 194, 512);
        ring_zero<<<(2 * (2 * 194 + 2 * 192) * 8  + 255) / 256, 256, 0, stream>>>(A2b, 2, 194, 64);
        mfma_conv<4><<<swiz_grid(128, 8), 256, 0, stream>>>(X16i, Wr1h, br1, A1, 128, 512, 194, 194, 1, 128, 8);
        mfma_conv<2><<<swiz_grid(128, 2), 256, 0, stream>>>(A1, Wr2h, br2, A2b, 512, 64, 194, 194, 1, 128, 2);
        for (int b = 0; b < 2; ++b)
            conv3_tanh<<<144, 256, 0, stream>>>(A2b + (size_t)b * 194 * 194 * 64, Wr3h, br3,
                                                out + b * 36864);
    } else {
        for (int b = 0; b < 2; ++b) {
            ring_zero<<<(1 * (2 * 194 + 2 * 192) * 64 + 255) / 256, 256, 0, stream>>>(A1, 1, 194, 512);
            ring_zero<<<(1 * (2 * 194 + 2 * 192) * 8  + 255) / 256, 256, 0, stream>>>(A2, 1, 194, 64);
            mfma_conv<4><<<swiz_grid(64, 8), 256, 0, stream>>>(X16i + (size_t)b * 194 * 194 * 128,
                                                               Wr1h, br1, A1, 128, 512, 194, 194, 1, 64, 8);
            mfma_conv<2><<<swiz_grid(64, 2), 256, 0, stream>>>(A1, Wr2h, br2, A2, 512, 64, 194, 194, 1, 64, 2);
            conv3_tanh<<<144, 256, 0, stream>>>(A2, Wr3h, br3, out + b * 36864);
        }
    }
}